// Round 10
// baseline (219.014 us; speedup 1.0000x reference)
//
#include <hip/hip_runtime.h>
#include <hip/hip_bf16.h>
#include <math.h>

namespace {

typedef unsigned short u16;
typedef __bf16 bf16x8 __attribute__((ext_vector_type(8)));
typedef float f32x4 __attribute__((ext_vector_type(4)));

constexpr int L_SEQ  = 2048;
constexpr int DPROJ  = 2568;
constexpr int OFF_X  = 1024;
constexpr int OFF_B  = 2048;
constexpr int OFF_C  = 2304;
constexpr int OFF_DT = 2560;
constexpr int SCHUNK = 16;
constexpr int NCH    = L_SEQ / SCHUNK;  // 128

__device__ inline u16 f2bf(float x) {
  unsigned u = __float_as_uint(x);
  unsigned r = u + 0x7FFFu + ((u >> 16) & 1u);
  return (u16)(r >> 16);
}
__device__ inline float bf2f(u16 h) {
  return __uint_as_float(((unsigned)h) << 16);
}

// ---------------------------------------------------------------------------
// f32 -> (bf16 hi, bf16 lo) split conversion (generic single-tensor).
// ---------------------------------------------------------------------------
__device__ inline void split_body(const float* __restrict__ src, int rows,
                                  int cols, int stride, int idx,
                                  u16* __restrict__ hi, u16* __restrict__ lo)
{
  int c4cnt = cols >> 2;
  int row = idx / c4cnt;
  int c4  = (idx % c4cnt) << 2;
  float4 v = make_float4(0.f, 0.f, 0.f, 0.f);
  if (row < rows) v = *(const float4*)(src + (size_t)row * stride + c4);
  float x[4] = {v.x, v.y, v.z, v.w};
  u16 h[4], l[4];
#pragma unroll
  for (int j = 0; j < 4; ++j) {
    h[j] = f2bf(x[j]);
    l[j] = f2bf(x[j] - bf2f(h[j]));
  }
  size_t off = (size_t)row * cols + c4;
  *(ushort4*)(hi + off) = make_ushort4(h[0], h[1], h[2], h[3]);
  *(ushort4*)(lo + off) = make_ushort4(l[0], l[1], l[2], l[3]);
}

__global__ __launch_bounds__(256)
void convert_split(const float* __restrict__ src, int rows, int cols, int stride,
                   int rows_pad, u16* __restrict__ hi, u16* __restrict__ lo)
{
  int idx = blockIdx.x * 256 + threadIdx.x;
  if (idx >= rows_pad * (cols >> 2)) return;
  split_body(src, rows, cols, stride, idx, hi, lo);
}

// All four weight tensors in one launch (block-range dispatch).
// W_in: blocks [0,1344) ; W_xup: [1344,1352) ; W_ydown: [1352,1360) ;
// W_out: [1360,1872).
__global__ __launch_bounds__(256)
void convert_weights(const float* __restrict__ W_in, const float* __restrict__ W_xup,
                     const float* __restrict__ W_ydown, const float* __restrict__ W_out,
                     u16* __restrict__ win_hi, u16* __restrict__ win_lo,
                     u16* __restrict__ wxup_hi, u16* __restrict__ wxup_lo,
                     u16* __restrict__ wyd_hi, u16* __restrict__ wyd_lo,
                     u16* __restrict__ wout_hi, u16* __restrict__ wout_lo)
{
  int b = blockIdx.x;
  if (b < 1344) {
    split_body(W_in, 2568, 512, 512, b * 256 + threadIdx.x, win_hi, win_lo);
  } else if (b < 1352) {
    split_body(W_xup, 128, 64, 64, (b - 1344) * 256 + threadIdx.x, wxup_hi, wxup_lo);
  } else if (b < 1360) {
    split_body(W_ydown, 64, 128, 128, (b - 1352) * 256 + threadIdx.x, wyd_hi, wyd_lo);
  } else {
    split_body(W_out, 512, 1024, 1024, (b - 1360) * 256 + threadIdx.x, wout_hi, wout_lo);
  }
}

// ---------------------------------------------------------------------------
// async global->LDS, 16B per lane.
// ---------------------------------------------------------------------------
__device__ inline void gload16(const u16* g, u16* l) {
  __builtin_amdgcn_global_load_lds(
      (const __attribute__((address_space(1))) unsigned int*)g,
      (__attribute__((address_space(3))) unsigned int*)l, 16, 0, 0);
}

// XCD-aware bijective swizzle (requires nwg % 8 == 0; all our grids comply).
__device__ inline void xcd_swizzle(int& bx, int& by, int& bz) {
  int nx = gridDim.x, ny = gridDim.y;
  int nwg = nx * ny * gridDim.z;
  int flat = blockIdx.x + nx * (blockIdx.y + ny * blockIdx.z);
  int cpx = nwg >> 3;
  int swz = (flat & 7) * cpx + (flat >> 3);
  bx = swz % nx;
  int r = swz / nx;
  by = r % ny;
  bz = r / ny;
}

// ---------------------------------------------------------------------------
// Split-bf16 MFMA GEMM: C[M,N] = A[M,K] * B[N,K]^T (+bias).
// Wave computes 64x64 (4x4 frags of 16x16x32). A*B ~= Ah*Bh + Al*Bh + Ah*Bl.
// global_load_lds staging into fragment-ordered LDS (conflict-free), double
// buffered. GATE=true: ydown-specific fused epilogue writing yg bf16 hi/lo.
// ---------------------------------------------------------------------------
template<int WMW, int WNW, bool GATE>
__global__ __launch_bounds__(64 * WMW * WNW)
void gemm_mfma(const u16* __restrict__ Ah, const u16* __restrict__ Al,
               const u16* __restrict__ Bh, const u16* __restrict__ Bl,
               const float* __restrict__ bias,
               float* __restrict__ C, int ldc, int N,
               int Kstride, int Klen, size_t c_slice,
               const float* __restrict__ Dv,
               const u16* __restrict__ xs_hi, const u16* __restrict__ xs_lo,
               const float* __restrict__ projz,
               u16* __restrict__ yg_hi, u16* __restrict__ yg_lo)
{
  constexpr int BM = 64 * WMW, BN = 64 * WNW;
  constexpr int WAVES = WMW * WNW;
  constexpr int RG_A = BM / 16, RG_B = BN / 16;
  constexpr int NG = 2 * RG_A + 2 * RG_B;
  constexpr int GPW = NG / WAVES;
  static_assert(NG % WAVES == 0, "");

  __shared__ u16 sAB[2][NG * 512];

  int bx, by, bz;
  xcd_swizzle(bx, by, bz);

  const int tid  = threadIdx.x;
  const int wave = tid >> 6;
  const int lane = tid & 63;
  const int wm   = wave % WMW;
  const int wn   = wave / WMW;
  const int bm   = bx * BM;
  const int bn   = by * BN;
  const int koff = bz * Klen;
  const int lrow = lane & 15;
  const int lkc  = lane >> 4;
  const int sr   = lane >> 2;
  const int sk8  = (lane & 3) * 8;

  const u16* gptr[GPW];
#pragma unroll
  for (int t = 0; t < GPW; ++t) {
    int g = wave * GPW + t;
    const u16* base;
    int rowbase;
    if (g < 2 * RG_A) {
      int hl = g / RG_A, i = g % RG_A;
      base = hl ? Al : Ah;  rowbase = bm + i * 16;
    } else {
      int g2 = g - 2 * RG_A;
      int hl = g2 / RG_B, i = g2 % RG_B;
      base = hl ? Bl : Bh;  rowbase = bn + i * 16;
    }
    gptr[t] = base + (size_t)(rowbase + sr) * Kstride + koff + sk8;
  }

  f32x4 acc[4][4];
#pragma unroll
  for (int i = 0; i < 4; ++i)
#pragma unroll
    for (int j = 0; j < 4; ++j) acc[i][j] = (f32x4){0.f, 0.f, 0.f, 0.f};

#define STAGE(b, kk)                                             \
  {                                                              \
    _Pragma("unroll")                                            \
    for (int t = 0; t < GPW; ++t)                                \
      gload16(gptr[t] + (kk), &sAB[b][(wave * GPW + t) * 512]);  \
  }

  STAGE(0, 0);
  asm volatile("s_waitcnt vmcnt(0)" ::: "memory");
  __syncthreads();

  int buf = 0;
  for (int k0 = 0; k0 < Klen; k0 += 32) {
    if (k0 + 32 < Klen) STAGE(buf ^ 1, k0 + 32);

    const u16* sb = sAB[buf];
    bf16x8 a_h[4], a_l[4], b_h[4], b_l[4];
#pragma unroll
    for (int i = 0; i < 4; ++i) {
      a_h[i] = *(const bf16x8*)&sb[(0 * RG_A + wm * 4 + i) * 512 + lrow * 32 + lkc * 8];
      a_l[i] = *(const bf16x8*)&sb[(1 * RG_A + wm * 4 + i) * 512 + lrow * 32 + lkc * 8];
      b_h[i] = *(const bf16x8*)&sb[(2 * RG_A + 0 * RG_B + wn * 4 + i) * 512 + lrow * 32 + lkc * 8];
      b_l[i] = *(const bf16x8*)&sb[(2 * RG_A + 1 * RG_B + wn * 4 + i) * 512 + lrow * 32 + lkc * 8];
    }
#pragma unroll
    for (int i = 0; i < 4; ++i)
#pragma unroll
      for (int j = 0; j < 4; ++j) {
        acc[i][j] = __builtin_amdgcn_mfma_f32_16x16x32_bf16(a_h[i], b_h[j], acc[i][j], 0, 0, 0);
        acc[i][j] = __builtin_amdgcn_mfma_f32_16x16x32_bf16(a_l[i], b_h[j], acc[i][j], 0, 0, 0);
        acc[i][j] = __builtin_amdgcn_mfma_f32_16x16x32_bf16(a_h[i], b_l[j], acc[i][j], 0, 0, 0);
      }

    asm volatile("s_waitcnt vmcnt(0)" ::: "memory");
    __syncthreads();
    buf ^= 1;
  }
#undef STAGE

  const int r0 = (lane >> 4) * 4;
  if (!GATE) {
    float* Cs = C + (size_t)bz * c_slice;
#pragma unroll
    for (int j = 0; j < 4; ++j) {
      int col = bn + wn * 64 + j * 16 + lrow;
      if (col >= N) continue;
      float bv = bias ? bias[col] : 0.f;
#pragma unroll
      for (int i = 0; i < 4; ++i) {
        int rowb = bm + wm * 64 + i * 16 + r0;
#pragma unroll
        for (int r = 0; r < 4; ++r)
          Cs[(size_t)(rowb + r) * ldc + col] = acc[i][j][r] + bv;
      }
    }
  } else {
#pragma unroll
    for (int j = 0; j < 4; ++j) {
      int col = bn + wn * 64 + j * 16 + lrow;     // p in [0,64)
#pragma unroll
      for (int i = 0; i < 4; ++i) {
        int rowb = bm + wm * 64 + i * 16 + r0;
#pragma unroll
        for (int r = 0; r < 4; ++r) {
          int row = rowb + r;                     // l*16 + h
          int l = row >> 4, h = row & 15;
          size_t ei = (size_t)l * 1024 + (h << 6) + col;
          float xsv = bf2f(xs_hi[ei]) + bf2f(xs_lo[ei]);
          float z = projz[(size_t)l * DPROJ + (h << 6) + col];
          float v = (acc[i][j][r] + Dv[h] * xsv) * (z / (1.f + expf(-z)));
          u16 hh = f2bf(v);
          yg_hi[ei] = hh;
          yg_lo[ei] = f2bf(v - bf2f(hh));
        }
      }
    }
  }
}

// ---------------------------------------------------------------------------
// out = sum of 4 split-K partials (float4-vectorized).
// ---------------------------------------------------------------------------
__global__ __launch_bounds__(256)
void reduce4_kernel(const float* __restrict__ p, float* __restrict__ o)
{
  const int n = L_SEQ * 512 / 4;
  int i = blockIdx.x * 256 + threadIdx.x;
  if (i >= n) return;
  float4 a = ((const float4*)p)[i];
  float4 b = ((const float4*)p)[i + n];
  float4 c = ((const float4*)p)[i + 2 * n];
  float4 d = ((const float4*)p)[i + 3 * n];
  float4 r;
  r.x = (a.x + b.x) + (c.x + d.x);
  r.y = (a.y + b.y) + (c.y + d.y);
  r.z = (a.z + b.z) + (c.z + d.z);
  r.w = (a.w + b.w) + (c.w + d.w);
  ((float4*)o)[i] = r;
}

// ---------------------------------------------------------------------------
// dt / lam in EXACT f32 straight from u . W_in rows, then coefficients.
// ---------------------------------------------------------------------------
__global__ __launch_bounds__(256)
void dtlam_kernel(const float* __restrict__ u, const float* __restrict__ W_in,
                  const float* __restrict__ b_in, const float* __restrict__ A_log,
                  float* __restrict__ dtg, float* __restrict__ alphag,
                  float* __restrict__ c0g, float* __restrict__ c1g)
{
  int idx = blockIdx.x * 256 + threadIdx.x;      // L*G = 8192
  if (idx >= L_SEQ * 4) return;
  int l = idx >> 2, g = idx & 3;
  const float4* ur = (const float4*)(u + (size_t)l * 512);
  const float4* wd = (const float4*)(W_in + (size_t)(OFF_DT + g) * 512);
  const float4* wl = (const float4*)(W_in + (size_t)(OFF_DT + 4 + g) * 512);
  float sd = 0.f, sl = 0.f;
  for (int k = 0; k < 128; ++k) {
    float4 a = ur[k], b = wd[k], c = wl[k];
    sd += a.x * b.x + a.y * b.y + a.z * b.z + a.w * b.w;
    sl += a.x * c.x + a.y * c.y + a.z * c.z + a.w * c.w;
  }
  sd += b_in[OFF_DT + g];
  sl += b_in[OFF_DT + 4 + g];
  float dt  = (sd > 20.f) ? sd : log1pf(expf(sd));
  float lam = 1.f / (1.f + expf(-sl));
  float Ag  = -expf(A_log[g]);
  float al  = expf(dt * Ag);
  dtg[idx]    = dt;
  alphag[idx] = al;
  c0g[idx]    = 1.f - lam;
  c1g[idx]    = lam * al;
}

// ---------------------------------------------------------------------------
// f64 inclusive cumsum of dt over L, per group.  grid=4 (g), block=256.
// ---------------------------------------------------------------------------
__global__ __launch_bounds__(256)
void cumsum_dt_kernel(const float* __restrict__ dtg, float* __restrict__ cumdt)
{
  const int g = blockIdx.x;
  const int t = threadIdx.x;
  constexpr int PER = L_SEQ / 256;  // 8
  __shared__ double ps[256];
  float loc[PER];
  double s = 0.0;
  int l0 = t * PER;
  for (int i = 0; i < PER; ++i) {
    loc[i] = dtg[(l0 + i) * 4 + g];
    s += (double)loc[i];
  }
  ps[t] = s;
  __syncthreads();
  for (int off = 1; off < 256; off <<= 1) {
    double v = (t >= off) ? ps[t - off] : 0.0;
    __syncthreads();
    ps[t] += v;
    __syncthreads();
  }
  double c = ps[t] - s;  // exclusive prefix
  for (int i = 0; i < PER; ++i) {
    c += (double)loc[i];
    cumdt[(l0 + i) * 4 + g] = (float)c;
  }
}

// ---------------------------------------------------------------------------
// Per-token: silu(xp) -> xs hi/lo split ; rms+bias+rope for B/C.
// ---------------------------------------------------------------------------
__global__ __launch_bounds__(256)
void pertoken_kernel(const float* __restrict__ proj,
                     const float* __restrict__ cumdt,
                     const float* __restrict__ theta_log,
                     const float* __restrict__ norm_B_w,
                     const float* __restrict__ norm_C_w,
                     const float* __restrict__ bias_B,
                     const float* __restrict__ bias_C,
                     u16* __restrict__ xs_hi, u16* __restrict__ xs_lo,
                     float* __restrict__ Brot,
                     float* __restrict__ Crot)
{
  const int l = blockIdx.x;
  const int t = threadIdx.x;
  const size_t prow = (size_t)l * DPROJ;

  for (int i = t; i < 1024; i += 256) {
    float x = proj[prow + OFF_X + i];
    float s = x / (1.f + expf(-x));
    u16 hh = f2bf(s);
    xs_hi[(size_t)l * 1024 + i] = hh;
    xs_lo[(size_t)l * 1024 + i] = f2bf(s - bf2f(hh));
  }

  const int g = t >> 6;
  const int e = t & 63;
  float bv = proj[prow + OFF_B + t];
  float cv = proj[prow + OFF_C + t];
  float ssb = bv * bv, ssc = cv * cv;
#pragma unroll
  for (int m = 1; m <= 32; m <<= 1) {
    ssb += __shfl_xor(ssb, m, 64);
    ssc += __shfl_xor(ssc, m, 64);
  }
  float nb = bv * rsqrtf(ssb * (1.f / 64.f) + 1e-5f) * norm_B_w[e] + bias_B[t];
  float nc = cv * rsqrtf(ssc * (1.f / 64.f) + 1e-5f) * norm_C_w[e] + bias_C[t];

  float ang = expf(theta_log[g * 16 + (e >> 2)]) * cumdt[l * 4 + g];
  float ca, sa;
  sincosf(ang, &sa, &ca);   // sincosf writes SIN to 1st ptr, COS to 2nd
  float nb2 = __shfl_xor(nb, 2, 64);
  float nc2 = __shfl_xor(nc, 2, 64);
  bool isre = ((e >> 1) & 1) == 0;
  float Bo, Co;
  if (isre) {
    Bo = nb * ca + nb2 * sa;   // theta = -ang
    Co = nc * ca - nc2 * sa;   // theta = +ang
  } else {
    Bo = nb * ca - nb2 * sa;
    Co = nc * ca + nc2 * sa;
  }
  Brot[(size_t)l * 256 + t] = Bo;
  Crot[(size_t)l * 256 + t] = Co;
}

// ---------------------------------------------------------------------------
// Scan: lane = p, per-thread state H[n=0..31] + uprev[n].
// grid = (NCH, G), block = 256 (4 waves = 4 heads of group g).
// WITH_Y=true writes y directly as bf16 hi/lo split.
// ---------------------------------------------------------------------------
template<bool WITH_Y>
__global__ __launch_bounds__(256)
void scan_chunk(const float* __restrict__ Brot, const float* __restrict__ Crot,
                const float* __restrict__ xup,
                const float* __restrict__ dtg, const float* __restrict__ alphag,
                const float* __restrict__ c0g, const float* __restrict__ c1g,
                const float* __restrict__ hstates_in,
                float* __restrict__ hlast_out,
                u16* __restrict__ yhi, u16* __restrict__ ylo)
{
  const int c   = blockIdx.x;
  const int g   = blockIdx.y;
  const int wid = threadIdx.x >> 6;
  const int p   = threadIdx.x & 63;
  const int h   = g * 4 + wid;
  const int l0  = c * SCHUNK;

  __shared__ float Bs[SCHUNK][64];
  __shared__ float Cs[SCHUNK][64];
  __shared__ float als[SCHUNK], c0s[SCHUNK], c1s[SCHUNK];

  for (int i = threadIdx.x; i < SCHUNK * 64; i += 256) {
    int l = i >> 6, e = i & 63;
    float dt = dtg[(l0 + l) * 4 + g];
    Bs[l][e] = dt * Brot[(size_t)(l0 + l) * 256 + g * 64 + e];
    if (WITH_Y) Cs[l][e] = Crot[(size_t)(l0 + l) * 256 + g * 64 + e];
  }
  if (threadIdx.x < SCHUNK) {
    int l = threadIdx.x;
    als[l] = alphag[(l0 + l) * 4 + g];
    c0s[l] = c0g[(l0 + l) * 4 + g];
    c1s[l] = c1g[(l0 + l) * 4 + g];
  }
  __syncthreads();

  float H[32], up[32];
  if (WITH_Y) {
    const float* hs = &hstates_in[(((size_t)c * 16 + h) * 64 + p) * 32];
#pragma unroll
    for (int q = 0; q < 8; ++q) {
      float4 v = *reinterpret_cast<const float4*>(hs + 4 * q);
      H[4 * q] = v.x; H[4 * q + 1] = v.y; H[4 * q + 2] = v.z; H[4 * q + 3] = v.w;
    }
  } else {
#pragma unroll
    for (int n = 0; n < 32; ++n) H[n] = 0.f;
  }

  if (c > 0) {
    const int lm = l0 - 1;
    const float dtm = dtg[lm * 4 + g];
    float2 X = *reinterpret_cast<const float2*>(&xup[((size_t)lm * 16 + h) * 128 + 2 * p]);
    float x0 = dtm * X.x, x1 = dtm * X.y;
#pragma unroll
    for (int n = 0; n < 32; ++n) {
      float2 Bv = *reinterpret_cast<const float2*>(&Brot[(size_t)lm * 256 + g * 64 + 2 * n]);
      up[n] = Bv.x * x0 + Bv.y * x1;
    }
  } else {
#pragma unroll
    for (int n = 0; n < 32; ++n) up[n] = 0.f;
  }

  for (int l = 0; l < SCHUNK; ++l) {
    float2 X = *reinterpret_cast<const float2*>(
        &xup[((size_t)(l0 + l) * 16 + h) * 128 + 2 * p]);
    const float al = als[l], cc0 = c0s[l], cc1 = c1s[l];
    float y0 = 0.f, y1 = 0.f;
#pragma unroll
    for (int n2 = 0; n2 < 16; ++n2) {
      float4 Bv = *reinterpret_cast<const float4*>(&Bs[l][4 * n2]);
      float uin0 = Bv.x * X.x + Bv.y * X.y;
      float uin1 = Bv.z * X.x + Bv.w * X.y;
      float ue0 = cc0 * uin0 + cc1 * up[2 * n2];
      float ue1 = cc0 * uin1 + cc1 * up[2 * n2 + 1];
      H[2 * n2]     = al * H[2 * n2]     + ue0;
      H[2 * n2 + 1] = al * H[2 * n2 + 1] + ue1;
      up[2 * n2] = uin0; up[2 * n2 + 1] = uin1;
      if (WITH_Y) {
        float4 Cv = *reinterpret_cast<const float4*>(&Cs[l][4 * n2]);
        y0 = fmaf(H[2 * n2], Cv.x, fmaf(H[2 * n2 + 1], Cv.z, y0));
        y1 = fmaf(H[2 * n2], Cv.y, fmaf(H[2 * n2 + 1], Cv.w, y1));
      }
    }
    if (WITH_Y) {
      size_t ofs = ((size_t)(l0 + l) * 16 + h) * 128 + 2 * p;
      u16 h0 = f2bf(y0), h1 = f2bf(y1);
      *(ushort2*)&yhi[ofs] = make_ushort2(h0, h1);
      *(ushort2*)&ylo[ofs] = make_ushort2(f2bf(y0 - bf2f(h0)), f2bf(y1 - bf2f(h1)));
    }
  }

  if (!WITH_Y) {
    float* hl = &hlast_out[(((size_t)c * 16 + h) * 64 + p) * 32];
#pragma unroll
    for (int q = 0; q < 8; ++q)
      *reinterpret_cast<float4*>(hl + 4 * q) =
          make_float4(H[4 * q], H[4 * q + 1], H[4 * q + 2], H[4 * q + 3]);
  }
}

// ---------------------------------------------------------------------------
// Scan pass B: cross-chunk combine -> h_states (state entering each chunk).
// ---------------------------------------------------------------------------
__global__ __launch_bounds__(256)
void scan_passB(const float* __restrict__ hlast, const float* __restrict__ cumdt,
                const float* __restrict__ A_log, float* __restrict__ hstates)
{
  int idx = blockIdx.x * 256 + threadIdx.x;   // H * P * N = 32768
  int h = idx >> 11;
  int rem = idx & 2047;
  int g = h >> 2;
  float Ag = -expf(A_log[g]);
  float s = 0.f;
  for (int c = 0; c < NCH; ++c) {
    hstates[((size_t)c * 16 + h) * 2048 + rem] = s;
    float sd = cumdt[(c * SCHUNK + SCHUNK - 1) * 4 + g]
             - (c > 0 ? cumdt[(c * SCHUNK - 1) * 4 + g] : 0.f);
    float dec = expf(Ag * sd);
    s = s * dec + hlast[((size_t)c * 16 + h) * 2048 + rem];
  }
}

}  // namespace

extern "C" void kernel_launch(void* const* d_in, const int* in_sizes, int n_in,
                              void* d_out, int out_size, void* d_ws, size_t ws_size,
                              hipStream_t stream)
{
  const float* u         = (const float*)d_in[0];
  const float* W_in      = (const float*)d_in[1];
  const float* b_in      = (const float*)d_in[2];
  const float* W_xup     = (const float*)d_in[3];
  const float* W_ydown   = (const float*)d_in[4];
  const float* A_log     = (const float*)d_in[5];
  const float* theta_log = (const float*)d_in[6];
  const float* Dvec      = (const float*)d_in[7];
  const float* norm_B_w  = (const float*)d_in[8];
  const float* norm_C_w  = (const float*)d_in[9];
  const float* bias_B    = (const float*)d_in[10];
  const float* bias_C    = (const float*)d_in[11];
  const float* W_out     = (const float*)d_in[12];
  float* out = (float*)d_out;

  // ---- f32 workspace carve (floats) ----
  float* proj    = (float*)d_ws;                    // 2048*2568
  float* xsreg   = proj    + (size_t)L_SEQ * DPROJ; // 2048*1024 floats (xs hi+lo u16)
  float* dtg     = xsreg   + (size_t)L_SEQ * 1024;  // 2048*4 each
  float* alphag  = dtg     + L_SEQ * 4;
  float* c0g     = alphag  + L_SEQ * 4;
  float* c1g     = c0g     + L_SEQ * 4;
  float* cumdt   = c1g     + L_SEQ * 4;
  float* Brot    = cumdt   + L_SEQ * 4;             // 2048*256
  float* Crot    = Brot    + (size_t)L_SEQ * 256;
  float* xup     = Crot    + (size_t)L_SEQ * 256;   // 32768*128
  float* y128s   = xup     + (size_t)32768 * 128;   // slot: 32768*128 floats
  float* rAf     = y128s   + (size_t)32768 * 128;   // u16 region (see below)
  float* hlast   = rAf     + (size_t)5100000;       // NCH*16*2048 = 4.19M floats
  float* hstates = hlast   + (size_t)NCH * 16 * 2048;
  float* partials = y128s;                          // alias (y128 bf16 dead by out gemm)

  // xs hi/lo live in the xsreg slot (u16 planes)
  u16* xs_hi = (u16*)xsreg;
  u16* xs_lo = xs_hi + (size_t)L_SEQ * 1024;
  // y128 hi/lo live in the y128s slot
  u16* y128_hi = (u16*)y128s;
  u16* y128_lo = y128_hi + (size_t)32768 * 128;

  // ---- bf16 hi/lo region A (u16): persistent weights + u (dead after proj
  //      gemm) + yg. All non-overlapping. ----
  u16* rA = (u16*)rAf;
  u16* win_hi  = rA;                                  // 2688*512
  u16* win_lo  = win_hi  + (size_t)2688 * 512;
  u16* wxup_hi = win_lo  + (size_t)2688 * 512;        // 128*64
  u16* wxup_lo = wxup_hi + (size_t)128 * 64;
  u16* wyd_hi  = wxup_lo + (size_t)128 * 64;          // 64*128
  u16* wyd_lo  = wyd_hi  + (size_t)64 * 128;
  u16* wout_hi = wyd_lo  + (size_t)64 * 128;          // 512*1024
  u16* wout_lo = wout_hi + (size_t)512 * 1024;
  u16* u_hi    = wout_lo + (size_t)512 * 1024;        // 2048*512
  u16* u_lo    = u_hi    + (size_t)2048 * 512;
  u16* yg_hi   = u_lo    + (size_t)2048 * 512;        // 2048*1024
  u16* yg_lo   = yg_hi   + (size_t)2048 * 1024;
  // total = 10,125,312 u16 = 5,062,656 floats < 5,100,000 reserved

  // 1. all weight converts in one launch; u convert; proj GEMM
  convert_weights<<<dim3(1872), 256, 0, stream>>>(
      W_in, W_xup, W_ydown, W_out,
      win_hi, win_lo, wxup_hi, wxup_lo, wyd_hi, wyd_lo, wout_hi, wout_lo);
  convert_split<<<dim3(1024), 256, 0, stream>>>(u, 2048, 512, 512, 2048, u_hi, u_lo);
  gemm_mfma<2, 2, false><<<dim3(16, 21, 1), 256, 0, stream>>>(
      u_hi, u_lo, win_hi, win_lo, b_in, proj, DPROJ, DPROJ, 512, 512, 0,
      nullptr, nullptr, nullptr, nullptr, nullptr, nullptr);

  // 2. dt/lam exact-f32; 3. f64 cumsum
  dtlam_kernel<<<dim3(32), 256, 0, stream>>>(u, W_in, b_in, A_log, dtg, alphag, c0g, c1g);
  cumsum_dt_kernel<<<dim3(4), 256, 0, stream>>>(dtg, cumdt);

  // 4. per-token: silu(xp) -> xs hi/lo, rms+bias+rope -> Brot/Crot
  pertoken_kernel<<<dim3(L_SEQ), 256, 0, stream>>>(
      proj, cumdt, theta_log, norm_B_w, norm_C_w, bias_B, bias_C,
      xs_hi, xs_lo, Brot, Crot);

  // 5. x_up = xs @ W_xup^T (MFMA)
  gemm_mfma<2, 2, false><<<dim3(256, 1, 1), 256, 0, stream>>>(
      xs_hi, xs_lo, wxup_hi, wxup_lo, nullptr, xup, 128, 128, 64, 64, 0,
      nullptr, nullptr, nullptr, nullptr, nullptr, nullptr);

  // 6-8. chunked scan (state-in-registers); scanC emits y128 bf16 hi/lo
  scan_chunk<false><<<dim3(NCH, 4), 256, 0, stream>>>(
      Brot, Crot, xup, dtg, alphag, c0g, c1g, nullptr, hlast, nullptr, nullptr);
  scan_passB<<<dim3(128), 256, 0, stream>>>(hlast, cumdt, A_log, hstates);
  scan_chunk<true><<<dim3(NCH, 4), 256, 0, stream>>>(
      Brot, Crot, xup, dtg, alphag, c0g, c1g, hstates, nullptr, y128_hi, y128_lo);

  // 9+10. ydown GEMM with fused gate epilogue -> yg hi/lo directly
  gemm_mfma<2, 1, true><<<dim3(256, 1, 1), 128, 0, stream>>>(
      y128_hi, y128_lo, wyd_hi, wyd_lo, nullptr, nullptr, 0, 64, 128, 128, 0,
      Dvec, xs_hi, xs_lo, proj, yg_hi, yg_lo);

  // 11. out = yg @ W_out^T (MFMA, split-K=4 into partials) ; reduce
  gemm_mfma<2, 2, false><<<dim3(16, 4, 4), 256, 0, stream>>>(
      yg_hi, yg_lo, wout_hi, wout_lo, nullptr, partials, 512, 512, 1024, 256,
      (size_t)L_SEQ * 512,
      nullptr, nullptr, nullptr, nullptr, nullptr, nullptr);
  reduce4_kernel<<<dim3(1024), 256, 0, stream>>>(partials, out);
}

// Round 11
// 189.047 us; speedup vs baseline: 1.1585x; 1.1585x over previous
//
#include <hip/hip_runtime.h>
#include <hip/hip_bf16.h>
#include <math.h>

namespace {

typedef unsigned short u16;
typedef __bf16 bf16x8 __attribute__((ext_vector_type(8)));
typedef float f32x4 __attribute__((ext_vector_type(4)));

constexpr int L_SEQ  = 2048;
constexpr int DPROJ  = 2568;
constexpr int OFF_X  = 1024;
constexpr int OFF_B  = 2048;
constexpr int OFF_C  = 2304;
constexpr int OFF_DT = 2560;
constexpr int SCHUNK = 16;
constexpr int NCH    = L_SEQ / SCHUNK;  // 128

__device__ inline u16 f2bf(float x) {
  unsigned u = __float_as_uint(x);
  unsigned r = u + 0x7FFFu + ((u >> 16) & 1u);
  return (u16)(r >> 16);
}
__device__ inline float bf2f(u16 h) {
  return __uint_as_float(((unsigned)h) << 16);
}

// ---------------------------------------------------------------------------
// f32 -> (bf16 hi, bf16 lo) split conversion (generic single-tensor).
// ---------------------------------------------------------------------------
__device__ inline void split_body(const float* __restrict__ src, int rows,
                                  int cols, int stride, int idx,
                                  u16* __restrict__ hi, u16* __restrict__ lo)
{
  int c4cnt = cols >> 2;
  int row = idx / c4cnt;
  int c4  = (idx % c4cnt) << 2;
  float4 v = make_float4(0.f, 0.f, 0.f, 0.f);
  if (row < rows) v = *(const float4*)(src + (size_t)row * stride + c4);
  float x[4] = {v.x, v.y, v.z, v.w};
  u16 h[4], l[4];
#pragma unroll
  for (int j = 0; j < 4; ++j) {
    h[j] = f2bf(x[j]);
    l[j] = f2bf(x[j] - bf2f(h[j]));
  }
  size_t off = (size_t)row * cols + c4;
  *(ushort4*)(hi + off) = make_ushort4(h[0], h[1], h[2], h[3]);
  *(ushort4*)(lo + off) = make_ushort4(l[0], l[1], l[2], l[3]);
}

__global__ __launch_bounds__(256)
void convert_split(const float* __restrict__ src, int rows, int cols, int stride,
                   int rows_pad, u16* __restrict__ hi, u16* __restrict__ lo)
{
  int idx = blockIdx.x * 256 + threadIdx.x;
  if (idx >= rows_pad * (cols >> 2)) return;
  split_body(src, rows, cols, stride, idx, hi, lo);
}

// All four weight tensors in one launch (block-range dispatch).
__global__ __launch_bounds__(256)
void convert_weights(const float* __restrict__ W_in, const float* __restrict__ W_xup,
                     const float* __restrict__ W_ydown, const float* __restrict__ W_out,
                     u16* __restrict__ win_hi, u16* __restrict__ win_lo,
                     u16* __restrict__ wxup_hi, u16* __restrict__ wxup_lo,
                     u16* __restrict__ wyd_hi, u16* __restrict__ wyd_lo,
                     u16* __restrict__ wout_hi, u16* __restrict__ wout_lo)
{
  int b = blockIdx.x;
  if (b < 1344) {
    split_body(W_in, 2568, 512, 512, b * 256 + threadIdx.x, win_hi, win_lo);
  } else if (b < 1352) {
    split_body(W_xup, 128, 64, 64, (b - 1344) * 256 + threadIdx.x, wxup_hi, wxup_lo);
  } else if (b < 1360) {
    split_body(W_ydown, 64, 128, 128, (b - 1352) * 256 + threadIdx.x, wyd_hi, wyd_lo);
  } else {
    split_body(W_out, 512, 1024, 1024, (b - 1360) * 256 + threadIdx.x, wout_hi, wout_lo);
  }
}

// ---------------------------------------------------------------------------
// async global->LDS, 16B per lane.
// ---------------------------------------------------------------------------
__device__ inline void gload16(const u16* g, u16* l) {
  __builtin_amdgcn_global_load_lds(
      (const __attribute__((address_space(1))) unsigned int*)g,
      (__attribute__((address_space(3))) unsigned int*)l, 16, 0, 0);
}

// XCD-aware bijective swizzle (requires nwg % 8 == 0; all our grids comply).
__device__ inline void xcd_swizzle(int& bx, int& by, int& bz) {
  int nx = gridDim.x, ny = gridDim.y;
  int nwg = nx * ny * gridDim.z;
  int flat = blockIdx.x + nx * (blockIdx.y + ny * blockIdx.z);
  int cpx = nwg >> 3;
  int swz = (flat & 7) * cpx + (flat >> 3);
  bx = swz % nx;
  int r = swz / nx;
  by = r % ny;
  bz = r / ny;
}

// ---------------------------------------------------------------------------
// Split-bf16 MFMA GEMM: C[M,N] = A[M,K] * B[N,K]^T (+bias).
// Wave computes 64x64 (4x4 frags of 16x16x32). A*B ~= Ah*Bh + Al*Bh + Ah*Bl.
// global_load_lds staging into fragment-ordered LDS (conflict-free), double
// buffered. GATE=true: ydown-specific fused epilogue writing yg bf16 hi/lo.
// ---------------------------------------------------------------------------
template<int WMW, int WNW, bool GATE>
__global__ __launch_bounds__(64 * WMW * WNW)
void gemm_mfma(const u16* __restrict__ Ah, const u16* __restrict__ Al,
               const u16* __restrict__ Bh, const u16* __restrict__ Bl,
               const float* __restrict__ bias,
               float* __restrict__ C, int ldc, int N,
               int Kstride, int Klen, size_t c_slice,
               const float* __restrict__ Dv,
               const u16* __restrict__ xs_hi, const u16* __restrict__ xs_lo,
               const float* __restrict__ projz,
               u16* __restrict__ yg_hi, u16* __restrict__ yg_lo)
{
  constexpr int BM = 64 * WMW, BN = 64 * WNW;
  constexpr int WAVES = WMW * WNW;
  constexpr int RG_A = BM / 16, RG_B = BN / 16;
  constexpr int NG = 2 * RG_A + 2 * RG_B;
  constexpr int GPW = NG / WAVES;
  static_assert(NG % WAVES == 0, "");

  __shared__ u16 sAB[2][NG * 512];

  int bx, by, bz;
  xcd_swizzle(bx, by, bz);

  const int tid  = threadIdx.x;
  const int wave = tid >> 6;
  const int lane = tid & 63;
  const int wm   = wave % WMW;
  const int wn   = wave / WMW;
  const int bm   = bx * BM;
  const int bn   = by * BN;
  const int koff = bz * Klen;
  const int lrow = lane & 15;
  const int lkc  = lane >> 4;
  const int sr   = lane >> 2;
  const int sk8  = (lane & 3) * 8;

  const u16* gptr[GPW];
#pragma unroll
  for (int t = 0; t < GPW; ++t) {
    int g = wave * GPW + t;
    const u16* base;
    int rowbase;
    if (g < 2 * RG_A) {
      int hl = g / RG_A, i = g % RG_A;
      base = hl ? Al : Ah;  rowbase = bm + i * 16;
    } else {
      int g2 = g - 2 * RG_A;
      int hl = g2 / RG_B, i = g2 % RG_B;
      base = hl ? Bl : Bh;  rowbase = bn + i * 16;
    }
    gptr[t] = base + (size_t)(rowbase + sr) * Kstride + koff + sk8;
  }

  f32x4 acc[4][4];
#pragma unroll
  for (int i = 0; i < 4; ++i)
#pragma unroll
    for (int j = 0; j < 4; ++j) acc[i][j] = (f32x4){0.f, 0.f, 0.f, 0.f};

#define STAGE(b, kk)                                             \
  {                                                              \
    _Pragma("unroll")                                            \
    for (int t = 0; t < GPW; ++t)                                \
      gload16(gptr[t] + (kk), &sAB[b][(wave * GPW + t) * 512]);  \
  }

  STAGE(0, 0);
  asm volatile("s_waitcnt vmcnt(0)" ::: "memory");
  __syncthreads();

  int buf = 0;
  for (int k0 = 0; k0 < Klen; k0 += 32) {
    if (k0 + 32 < Klen) STAGE(buf ^ 1, k0 + 32);

    const u16* sb = sAB[buf];
    bf16x8 a_h[4], a_l[4], b_h[4], b_l[4];
#pragma unroll
    for (int i = 0; i < 4; ++i) {
      a_h[i] = *(const bf16x8*)&sb[(0 * RG_A + wm * 4 + i) * 512 + lrow * 32 + lkc * 8];
      a_l[i] = *(const bf16x8*)&sb[(1 * RG_A + wm * 4 + i) * 512 + lrow * 32 + lkc * 8];
      b_h[i] = *(const bf16x8*)&sb[(2 * RG_A + 0 * RG_B + wn * 4 + i) * 512 + lrow * 32 + lkc * 8];
      b_l[i] = *(const bf16x8*)&sb[(2 * RG_A + 1 * RG_B + wn * 4 + i) * 512 + lrow * 32 + lkc * 8];
    }
#pragma unroll
    for (int i = 0; i < 4; ++i)
#pragma unroll
      for (int j = 0; j < 4; ++j) {
        acc[i][j] = __builtin_amdgcn_mfma_f32_16x16x32_bf16(a_h[i], b_h[j], acc[i][j], 0, 0, 0);
        acc[i][j] = __builtin_amdgcn_mfma_f32_16x16x32_bf16(a_l[i], b_h[j], acc[i][j], 0, 0, 0);
        acc[i][j] = __builtin_amdgcn_mfma_f32_16x16x32_bf16(a_h[i], b_l[j], acc[i][j], 0, 0, 0);
      }

    asm volatile("s_waitcnt vmcnt(0)" ::: "memory");
    __syncthreads();
    buf ^= 1;
  }
#undef STAGE

  const int r0 = (lane >> 4) * 4;
  if (!GATE) {
    float* Cs = C + (size_t)bz * c_slice;
#pragma unroll
    for (int j = 0; j < 4; ++j) {
      int col = bn + wn * 64 + j * 16 + lrow;
      if (col >= N) continue;
      float bv = bias ? bias[col] : 0.f;
#pragma unroll
      for (int i = 0; i < 4; ++i) {
        int rowb = bm + wm * 64 + i * 16 + r0;
#pragma unroll
        for (int r = 0; r < 4; ++r)
          Cs[(size_t)(rowb + r) * ldc + col] = acc[i][j][r] + bv;
      }
    }
  } else {
#pragma unroll
    for (int j = 0; j < 4; ++j) {
      int col = bn + wn * 64 + j * 16 + lrow;     // p in [0,64)
#pragma unroll
      for (int i = 0; i < 4; ++i) {
        int rowb = bm + wm * 64 + i * 16 + r0;
#pragma unroll
        for (int r = 0; r < 4; ++r) {
          int row = rowb + r;                     // l*16 + h
          int l = row >> 4, h = row & 15;
          size_t ei = (size_t)l * 1024 + (h << 6) + col;
          float xsv = bf2f(xs_hi[ei]) + bf2f(xs_lo[ei]);
          float z = projz[(size_t)l * DPROJ + (h << 6) + col];
          float v = (acc[i][j][r] + Dv[h] * xsv) * (z / (1.f + expf(-z)));
          u16 hh = f2bf(v);
          yg_hi[ei] = hh;
          yg_lo[ei] = f2bf(v - bf2f(hh));
        }
      }
    }
  }
}

// ---------------------------------------------------------------------------
// out = sum of 4 split-K partials (float4-vectorized).
// ---------------------------------------------------------------------------
__global__ __launch_bounds__(256)
void reduce4_kernel(const float* __restrict__ p, float* __restrict__ o)
{
  const int n = L_SEQ * 512 / 4;
  int i = blockIdx.x * 256 + threadIdx.x;
  if (i >= n) return;
  float4 a = ((const float4*)p)[i];
  float4 b = ((const float4*)p)[i + n];
  float4 c = ((const float4*)p)[i + 2 * n];
  float4 d = ((const float4*)p)[i + 3 * n];
  float4 r;
  r.x = (a.x + b.x) + (c.x + d.x);
  r.y = (a.y + b.y) + (c.y + d.y);
  r.z = (a.z + b.z) + (c.z + d.z);
  r.w = (a.w + b.w) + (c.w + d.w);
  ((float4*)o)[i] = r;
}

// ---------------------------------------------------------------------------
// dt / lam in EXACT f32 straight from u . W_in rows, then coefficients.
// ---------------------------------------------------------------------------
__global__ __launch_bounds__(256)
void dtlam_kernel(const float* __restrict__ u, const float* __restrict__ W_in,
                  const float* __restrict__ b_in, const float* __restrict__ A_log,
                  float* __restrict__ dtg, float* __restrict__ alphag,
                  float* __restrict__ c0g, float* __restrict__ c1g)
{
  int idx = blockIdx.x * 256 + threadIdx.x;      // L*G = 8192
  if (idx >= L_SEQ * 4) return;
  int l = idx >> 2, g = idx & 3;
  const float4* ur = (const float4*)(u + (size_t)l * 512);
  const float4* wd = (const float4*)(W_in + (size_t)(OFF_DT + g) * 512);
  const float4* wl = (const float4*)(W_in + (size_t)(OFF_DT + 4 + g) * 512);
  float sd = 0.f, sl = 0.f;
  for (int k = 0; k < 128; ++k) {
    float4 a = ur[k], b = wd[k], c = wl[k];
    sd += a.x * b.x + a.y * b.y + a.z * b.z + a.w * b.w;
    sl += a.x * c.x + a.y * c.y + a.z * c.z + a.w * c.w;
  }
  sd += b_in[OFF_DT + g];
  sl += b_in[OFF_DT + 4 + g];
  float dt  = (sd > 20.f) ? sd : log1pf(expf(sd));
  float lam = 1.f / (1.f + expf(-sl));
  float Ag  = -expf(A_log[g]);
  float al  = expf(dt * Ag);
  dtg[idx]    = dt;
  alphag[idx] = al;
  c0g[idx]    = 1.f - lam;
  c1g[idx]    = lam * al;
}

// ---------------------------------------------------------------------------
// f64 inclusive cumsum of dt over L, per group.  grid=4 (g), block=256.
// ---------------------------------------------------------------------------
__global__ __launch_bounds__(256)
void cumsum_dt_kernel(const float* __restrict__ dtg, float* __restrict__ cumdt)
{
  const int g = blockIdx.x;
  const int t = threadIdx.x;
  constexpr int PER = L_SEQ / 256;  // 8
  __shared__ double ps[256];
  float loc[PER];
  double s = 0.0;
  int l0 = t * PER;
  for (int i = 0; i < PER; ++i) {
    loc[i] = dtg[(l0 + i) * 4 + g];
    s += (double)loc[i];
  }
  ps[t] = s;
  __syncthreads();
  for (int off = 1; off < 256; off <<= 1) {
    double v = (t >= off) ? ps[t - off] : 0.0;
    __syncthreads();
    ps[t] += v;
    __syncthreads();
  }
  double c = ps[t] - s;  // exclusive prefix
  for (int i = 0; i < PER; ++i) {
    c += (double)loc[i];
    cumdt[(l0 + i) * 4 + g] = (float)c;
  }
}

// ---------------------------------------------------------------------------
// Per-token: silu(xp) -> xs hi/lo split ; rms+bias+rope for B/C.
// ---------------------------------------------------------------------------
__global__ __launch_bounds__(256)
void pertoken_kernel(const float* __restrict__ proj,
                     const float* __restrict__ cumdt,
                     const float* __restrict__ theta_log,
                     const float* __restrict__ norm_B_w,
                     const float* __restrict__ norm_C_w,
                     const float* __restrict__ bias_B,
                     const float* __restrict__ bias_C,
                     u16* __restrict__ xs_hi, u16* __restrict__ xs_lo,
                     float* __restrict__ Brot,
                     float* __restrict__ Crot)
{
  const int l = blockIdx.x;
  const int t = threadIdx.x;
  const size_t prow = (size_t)l * DPROJ;

  for (int i = t; i < 1024; i += 256) {
    float x = proj[prow + OFF_X + i];
    float s = x / (1.f + expf(-x));
    u16 hh = f2bf(s);
    xs_hi[(size_t)l * 1024 + i] = hh;
    xs_lo[(size_t)l * 1024 + i] = f2bf(s - bf2f(hh));
  }

  const int g = t >> 6;
  const int e = t & 63;
  float bv = proj[prow + OFF_B + t];
  float cv = proj[prow + OFF_C + t];
  float ssb = bv * bv, ssc = cv * cv;
#pragma unroll
  for (int m = 1; m <= 32; m <<= 1) {
    ssb += __shfl_xor(ssb, m, 64);
    ssc += __shfl_xor(ssc, m, 64);
  }
  float nb = bv * rsqrtf(ssb * (1.f / 64.f) + 1e-5f) * norm_B_w[e] + bias_B[t];
  float nc = cv * rsqrtf(ssc * (1.f / 64.f) + 1e-5f) * norm_C_w[e] + bias_C[t];

  float ang = expf(theta_log[g * 16 + (e >> 2)]) * cumdt[l * 4 + g];
  float ca, sa;
  sincosf(ang, &sa, &ca);   // sincosf writes SIN to 1st ptr, COS to 2nd
  float nb2 = __shfl_xor(nb, 2, 64);
  float nc2 = __shfl_xor(nc, 2, 64);
  bool isre = ((e >> 1) & 1) == 0;
  float Bo, Co;
  if (isre) {
    Bo = nb * ca + nb2 * sa;   // theta = -ang
    Co = nc * ca - nc2 * sa;   // theta = +ang
  } else {
    Bo = nb * ca - nb2 * sa;
    Co = nc * ca + nc2 * sa;
  }
  Brot[(size_t)l * 256 + t] = Bo;
  Crot[(size_t)l * 256 + t] = Co;
}

// ---------------------------------------------------------------------------
// Scan: lane = p, per-thread state H[n=0..31] + uprev[n].
// grid = (NCH, G), block = 256 (4 waves = 4 heads of group g).
// WITH_Y=true writes y directly as bf16 hi/lo split.
// ---------------------------------------------------------------------------
template<bool WITH_Y>
__global__ __launch_bounds__(256)
void scan_chunk(const float* __restrict__ Brot, const float* __restrict__ Crot,
                const float* __restrict__ xup,
                const float* __restrict__ dtg, const float* __restrict__ alphag,
                const float* __restrict__ c0g, const float* __restrict__ c1g,
                const float* __restrict__ hstates_in,
                float* __restrict__ hlast_out,
                u16* __restrict__ yhi, u16* __restrict__ ylo)
{
  const int c   = blockIdx.x;
  const int g   = blockIdx.y;
  const int wid = threadIdx.x >> 6;
  const int p   = threadIdx.x & 63;
  const int h   = g * 4 + wid;
  const int l0  = c * SCHUNK;

  __shared__ float Bs[SCHUNK][64];
  __shared__ float Cs[SCHUNK][64];
  __shared__ float als[SCHUNK], c0s[SCHUNK], c1s[SCHUNK];

  for (int i = threadIdx.x; i < SCHUNK * 64; i += 256) {
    int l = i >> 6, e = i & 63;
    float dt = dtg[(l0 + l) * 4 + g];
    Bs[l][e] = dt * Brot[(size_t)(l0 + l) * 256 + g * 64 + e];
    if (WITH_Y) Cs[l][e] = Crot[(size_t)(l0 + l) * 256 + g * 64 + e];
  }
  if (threadIdx.x < SCHUNK) {
    int l = threadIdx.x;
    als[l] = alphag[(l0 + l) * 4 + g];
    c0s[l] = c0g[(l0 + l) * 4 + g];
    c1s[l] = c1g[(l0 + l) * 4 + g];
  }
  __syncthreads();

  float H[32], up[32];
  if (WITH_Y) {
    const float* hs = &hstates_in[(((size_t)c * 16 + h) * 64 + p) * 32];
#pragma unroll
    for (int q = 0; q < 8; ++q) {
      float4 v = *reinterpret_cast<const float4*>(hs + 4 * q);
      H[4 * q] = v.x; H[4 * q + 1] = v.y; H[4 * q + 2] = v.z; H[4 * q + 3] = v.w;
    }
  } else {
#pragma unroll
    for (int n = 0; n < 32; ++n) H[n] = 0.f;
  }

  if (c > 0) {
    const int lm = l0 - 1;
    const float dtm = dtg[lm * 4 + g];
    float2 X = *reinterpret_cast<const float2*>(&xup[((size_t)lm * 16 + h) * 128 + 2 * p]);
    float x0 = dtm * X.x, x1 = dtm * X.y;
#pragma unroll
    for (int n = 0; n < 32; ++n) {
      float2 Bv = *reinterpret_cast<const float2*>(&Brot[(size_t)lm * 256 + g * 64 + 2 * n]);
      up[n] = Bv.x * x0 + Bv.y * x1;
    }
  } else {
#pragma unroll
    for (int n = 0; n < 32; ++n) up[n] = 0.f;
  }

  for (int l = 0; l < SCHUNK; ++l) {
    float2 X = *reinterpret_cast<const float2*>(
        &xup[((size_t)(l0 + l) * 16 + h) * 128 + 2 * p]);
    const float al = als[l], cc0 = c0s[l], cc1 = c1s[l];
    float y0 = 0.f, y1 = 0.f;
#pragma unroll
    for (int n2 = 0; n2 < 16; ++n2) {
      float4 Bv = *reinterpret_cast<const float4*>(&Bs[l][4 * n2]);
      float uin0 = Bv.x * X.x + Bv.y * X.y;
      float uin1 = Bv.z * X.x + Bv.w * X.y;
      float ue0 = cc0 * uin0 + cc1 * up[2 * n2];
      float ue1 = cc0 * uin1 + cc1 * up[2 * n2 + 1];
      H[2 * n2]     = al * H[2 * n2]     + ue0;
      H[2 * n2 + 1] = al * H[2 * n2 + 1] + ue1;
      up[2 * n2] = uin0; up[2 * n2 + 1] = uin1;
      if (WITH_Y) {
        float4 Cv = *reinterpret_cast<const float4*>(&Cs[l][4 * n2]);
        y0 = fmaf(H[2 * n2], Cv.x, fmaf(H[2 * n2 + 1], Cv.z, y0));
        y1 = fmaf(H[2 * n2], Cv.y, fmaf(H[2 * n2 + 1], Cv.w, y1));
      }
    }
    if (WITH_Y) {
      size_t ofs = ((size_t)(l0 + l) * 16 + h) * 128 + 2 * p;
      u16 h0 = f2bf(y0), h1 = f2bf(y1);
      *(ushort2*)&yhi[ofs] = make_ushort2(h0, h1);
      *(ushort2*)&ylo[ofs] = make_ushort2(f2bf(y0 - bf2f(h0)), f2bf(y1 - bf2f(h1)));
    }
  }

  if (!WITH_Y) {
    float* hl = &hlast_out[(((size_t)c * 16 + h) * 64 + p) * 32];
#pragma unroll
    for (int q = 0; q < 8; ++q)
      *reinterpret_cast<float4*>(hl + 4 * q) =
          make_float4(H[4 * q], H[4 * q + 1], H[4 * q + 2], H[4 * q + 3]);
  }
}

// ---------------------------------------------------------------------------
// Scan pass B: cross-chunk combine -> h_states (state entering each chunk).
// ILP-batched: 8 independent loads + 8 exp per step hide HBM latency under
// the serial FMA chain (loads/dec do not depend on s).
// ---------------------------------------------------------------------------
__global__ __launch_bounds__(256)
void scan_passB(const float* __restrict__ hlast, const float* __restrict__ cumdt,
                const float* __restrict__ A_log, float* __restrict__ hstates)
{
  int idx = blockIdx.x * 256 + threadIdx.x;   // H * P * N = 32768
  int h = idx >> 11;
  int rem = idx & 2047;
  int g = h >> 2;
  float Ag = -expf(A_log[g]);
  float s = 0.f;
  for (int c0 = 0; c0 < NCH; c0 += 8) {
    float hlv[8], dec[8];
#pragma unroll
    for (int j = 0; j < 8; ++j) {
      int c = c0 + j;
      hlv[j] = hlast[((size_t)c * 16 + h) * 2048 + rem];
      float sd = cumdt[(c * SCHUNK + SCHUNK - 1) * 4 + g]
               - (c > 0 ? cumdt[(c * SCHUNK - 1) * 4 + g] : 0.f);
      dec[j] = expf(Ag * sd);
    }
#pragma unroll
    for (int j = 0; j < 8; ++j) {
      hstates[((size_t)(c0 + j) * 16 + h) * 2048 + rem] = s;
      s = fmaf(s, dec[j], hlv[j]);
    }
  }
}

}  // namespace

extern "C" void kernel_launch(void* const* d_in, const int* in_sizes, int n_in,
                              void* d_out, int out_size, void* d_ws, size_t ws_size,
                              hipStream_t stream)
{
  const float* u         = (const float*)d_in[0];
  const float* W_in      = (const float*)d_in[1];
  const float* b_in      = (const float*)d_in[2];
  const float* W_xup     = (const float*)d_in[3];
  const float* W_ydown   = (const float*)d_in[4];
  const float* A_log     = (const float*)d_in[5];
  const float* theta_log = (const float*)d_in[6];
  const float* Dvec      = (const float*)d_in[7];
  const float* norm_B_w  = (const float*)d_in[8];
  const float* norm_C_w  = (const float*)d_in[9];
  const float* bias_B    = (const float*)d_in[10];
  const float* bias_C    = (const float*)d_in[11];
  const float* W_out     = (const float*)d_in[12];
  float* out = (float*)d_out;

  // ---- f32 workspace carve (floats) ----
  float* proj    = (float*)d_ws;                    // 2048*2568
  float* xsreg   = proj    + (size_t)L_SEQ * DPROJ; // 2048*1024 floats (xs hi+lo u16)
  float* dtg     = xsreg   + (size_t)L_SEQ * 1024;  // 2048*4 each
  float* alphag  = dtg     + L_SEQ * 4;
  float* c0g     = alphag  + L_SEQ * 4;
  float* c1g     = c0g     + L_SEQ * 4;
  float* cumdt   = c1g     + L_SEQ * 4;
  float* Brot    = cumdt   + L_SEQ * 4;             // 2048*256
  float* Crot    = Brot    + (size_t)L_SEQ * 256;
  float* xup     = Crot    + (size_t)L_SEQ * 256;   // 32768*128
  float* y128s   = xup     + (size_t)32768 * 128;   // slot: 32768*128 floats
  float* rAf     = y128s   + (size_t)32768 * 128;   // u16 region (see below)
  float* hlast   = rAf     + (size_t)5100000;       // NCH*16*2048 = 4.19M floats
  float* hstates = hlast   + (size_t)NCH * 16 * 2048;
  float* partials = y128s;                          // alias (y128 bf16 dead by out gemm)

  // xs hi/lo live in the xsreg slot (u16 planes)
  u16* xs_hi = (u16*)xsreg;
  u16* xs_lo = xs_hi + (size_t)L_SEQ * 1024;
  // y128 hi/lo live in the y128s slot
  u16* y128_hi = (u16*)y128s;
  u16* y128_lo = y128_hi + (size_t)32768 * 128;

  // ---- bf16 hi/lo region A (u16): persistent weights + u + yg ----
  u16* rA = (u16*)rAf;
  u16* win_hi  = rA;                                  // 2688*512
  u16* win_lo  = win_hi  + (size_t)2688 * 512;
  u16* wxup_hi = win_lo  + (size_t)2688 * 512;        // 128*64
  u16* wxup_lo = wxup_hi + (size_t)128 * 64;
  u16* wyd_hi  = wxup_lo + (size_t)128 * 64;          // 64*128
  u16* wyd_lo  = wyd_hi  + (size_t)64 * 128;
  u16* wout_hi = wyd_lo  + (size_t)64 * 128;          // 512*1024
  u16* wout_lo = wout_hi + (size_t)512 * 1024;
  u16* u_hi    = wout_lo + (size_t)512 * 1024;        // 2048*512
  u16* u_lo    = u_hi    + (size_t)2048 * 512;
  u16* yg_hi   = u_lo    + (size_t)2048 * 512;        // 2048*1024
  u16* yg_lo   = yg_hi   + (size_t)2048 * 1024;

  // 1. all weight converts in one launch; u convert; proj GEMM
  convert_weights<<<dim3(1872), 256, 0, stream>>>(
      W_in, W_xup, W_ydown, W_out,
      win_hi, win_lo, wxup_hi, wxup_lo, wyd_hi, wyd_lo, wout_hi, wout_lo);
  convert_split<<<dim3(1024), 256, 0, stream>>>(u, 2048, 512, 512, 2048, u_hi, u_lo);
  gemm_mfma<2, 2, false><<<dim3(16, 21, 1), 256, 0, stream>>>(
      u_hi, u_lo, win_hi, win_lo, b_in, proj, DPROJ, DPROJ, 512, 512, 0,
      nullptr, nullptr, nullptr, nullptr, nullptr, nullptr);

  // 2. dt/lam exact-f32; 3. f64 cumsum
  dtlam_kernel<<<dim3(32), 256, 0, stream>>>(u, W_in, b_in, A_log, dtg, alphag, c0g, c1g);
  cumsum_dt_kernel<<<dim3(4), 256, 0, stream>>>(dtg, cumdt);

  // 4. per-token: silu(xp) -> xs hi/lo, rms+bias+rope -> Brot/Crot
  pertoken_kernel<<<dim3(L_SEQ), 256, 0, stream>>>(
      proj, cumdt, theta_log, norm_B_w, norm_C_w, bias_B, bias_C,
      xs_hi, xs_lo, Brot, Crot);

  // 5. x_up = xs @ W_xup^T (MFMA)
  gemm_mfma<2, 2, false><<<dim3(256, 1, 1), 256, 0, stream>>>(
      xs_hi, xs_lo, wxup_hi, wxup_lo, nullptr, xup, 128, 128, 64, 64, 0,
      nullptr, nullptr, nullptr, nullptr, nullptr, nullptr);

  // 6-8. chunked scan (state-in-registers); scanC emits y128 bf16 hi/lo
  scan_chunk<false><<<dim3(NCH, 4), 256, 0, stream>>>(
      Brot, Crot, xup, dtg, alphag, c0g, c1g, nullptr, hlast, nullptr, nullptr);
  scan_passB<<<dim3(128), 256, 0, stream>>>(hlast, cumdt, A_log, hstates);
  scan_chunk<true><<<dim3(NCH, 4), 256, 0, stream>>>(
      Brot, Crot, xup, dtg, alphag, c0g, c1g, hstates, nullptr, y128_hi, y128_lo);

  // 9+10. ydown GEMM with fused gate epilogue -> yg hi/lo directly
  gemm_mfma<2, 1, true><<<dim3(256, 1, 1), 128, 0, stream>>>(
      y128_hi, y128_lo, wyd_hi, wyd_lo, nullptr, nullptr, 0, 64, 128, 128, 0,
      Dvec, xs_hi, xs_lo, proj, yg_hi, yg_lo);

  // 11. out = yg @ W_out^T (MFMA, split-K=4 into partials) ; reduce
  gemm_mfma<2, 2, false><<<dim3(16, 4, 4), 256, 0, stream>>>(
      yg_hi, yg_lo, wout_hi, wout_lo, nullptr, partials, 512, 512, 1024, 256,
      (size_t)L_SEQ * 512,
      nullptr, nullptr, nullptr, nullptr, nullptr, nullptr);
  reduce4_kernel<<<dim3(1024), 256, 0, stream>>>(partials, out);
}

// Round 12
// 162.580 us; speedup vs baseline: 1.3471x; 1.1628x over previous
//
#include <hip/hip_runtime.h>
#include <hip/hip_bf16.h>
#include <math.h>

namespace {

typedef unsigned short u16;
typedef __bf16 bf16x8 __attribute__((ext_vector_type(8)));
typedef float f32x4 __attribute__((ext_vector_type(4)));

constexpr int L_SEQ  = 2048;
constexpr int DPROJ  = 2568;
constexpr int OFF_X  = 1024;
constexpr int OFF_B  = 2048;
constexpr int OFF_C  = 2304;
constexpr int OFF_DT = 2560;
constexpr int SCHUNK = 16;
constexpr int NCH    = L_SEQ / SCHUNK;  // 128

__device__ inline u16 f2bf(float x) {
  unsigned u = __float_as_uint(x);
  unsigned r = u + 0x7FFFu + ((u >> 16) & 1u);
  return (u16)(r >> 16);
}
__device__ inline float bf2f(u16 h) {
  return __uint_as_float(((unsigned)h) << 16);
}

// ---------------------------------------------------------------------------
// f32 -> (bf16 hi, bf16 lo) split conversion body.
// ---------------------------------------------------------------------------
__device__ inline void split_body(const float* __restrict__ src, int rows,
                                  int cols, int stride, int idx,
                                  u16* __restrict__ hi, u16* __restrict__ lo)
{
  int c4cnt = cols >> 2;
  int row = idx / c4cnt;
  int c4  = (idx % c4cnt) << 2;
  float4 v = make_float4(0.f, 0.f, 0.f, 0.f);
  if (row < rows) v = *(const float4*)(src + (size_t)row * stride + c4);
  float x[4] = {v.x, v.y, v.z, v.w};
  u16 h[4], l[4];
#pragma unroll
  for (int j = 0; j < 4; ++j) {
    h[j] = f2bf(x[j]);
    l[j] = f2bf(x[j] - bf2f(h[j]));
  }
  size_t off = (size_t)row * cols + c4;
  *(ushort4*)(hi + off) = make_ushort4(h[0], h[1], h[2], h[3]);
  *(ushort4*)(lo + off) = make_ushort4(l[0], l[1], l[2], l[3]);
}

// All four weight tensors + u in one launch (block-range dispatch).
// W_in: [0,1344) ; W_xup: [1344,1352) ; W_ydown: [1352,1360) ;
// W_out: [1360,1872) ; u: [1872,2896).
__global__ __launch_bounds__(256)
void convert_all(const float* __restrict__ W_in, const float* __restrict__ W_xup,
                 const float* __restrict__ W_ydown, const float* __restrict__ W_out,
                 const float* __restrict__ u,
                 u16* __restrict__ win_hi, u16* __restrict__ win_lo,
                 u16* __restrict__ wxup_hi, u16* __restrict__ wxup_lo,
                 u16* __restrict__ wyd_hi, u16* __restrict__ wyd_lo,
                 u16* __restrict__ wout_hi, u16* __restrict__ wout_lo,
                 u16* __restrict__ u_hi, u16* __restrict__ u_lo)
{
  int b = blockIdx.x;
  if (b < 1344) {
    split_body(W_in, 2568, 512, 512, b * 256 + threadIdx.x, win_hi, win_lo);
  } else if (b < 1352) {
    split_body(W_xup, 128, 64, 64, (b - 1344) * 256 + threadIdx.x, wxup_hi, wxup_lo);
  } else if (b < 1360) {
    split_body(W_ydown, 64, 128, 128, (b - 1352) * 256 + threadIdx.x, wyd_hi, wyd_lo);
  } else if (b < 1872) {
    split_body(W_out, 512, 1024, 1024, (b - 1360) * 256 + threadIdx.x, wout_hi, wout_lo);
  } else {
    split_body(u, 2048, 512, 512, (b - 1872) * 256 + threadIdx.x, u_hi, u_lo);
  }
}

// ---------------------------------------------------------------------------
// async global->LDS, 16B per lane.
// ---------------------------------------------------------------------------
__device__ inline void gload16(const u16* g, u16* l) {
  __builtin_amdgcn_global_load_lds(
      (const __attribute__((address_space(1))) unsigned int*)g,
      (__attribute__((address_space(3))) unsigned int*)l, 16, 0, 0);
}

// XCD-aware bijective swizzle (requires nwg % 8 == 0; all our grids comply).
__device__ inline void xcd_swizzle(int& bx, int& by, int& bz) {
  int nx = gridDim.x, ny = gridDim.y;
  int nwg = nx * ny * gridDim.z;
  int flat = blockIdx.x + nx * (blockIdx.y + ny * blockIdx.z);
  int cpx = nwg >> 3;
  int swz = (flat & 7) * cpx + (flat >> 3);
  bx = swz % nx;
  int r = swz / nx;
  by = r % ny;
  bz = r / ny;
}

// ---------------------------------------------------------------------------
// Split-bf16 MFMA GEMM: C[M,N] = A[M,K] * B[N,K]^T (+bias).
// Wave computes 64x64 (4x4 frags of 16x16x32). A*B ~= Ah*Bh + Al*Bh + Ah*Bl.
// global_load_lds staging into fragment-ordered LDS (conflict-free), double
// buffered. GATE=true: ydown-specific fused epilogue writing yg bf16 hi/lo.
// ---------------------------------------------------------------------------
template<int WMW, int WNW, bool GATE>
__global__ __launch_bounds__(64 * WMW * WNW)
void gemm_mfma(const u16* __restrict__ Ah, const u16* __restrict__ Al,
               const u16* __restrict__ Bh, const u16* __restrict__ Bl,
               const float* __restrict__ bias,
               float* __restrict__ C, int ldc, int N,
               int Kstride, int Klen, size_t c_slice,
               const float* __restrict__ Dv,
               const u16* __restrict__ xs_hi, const u16* __restrict__ xs_lo,
               const float* __restrict__ projz,
               u16* __restrict__ yg_hi, u16* __restrict__ yg_lo)
{
  constexpr int BM = 64 * WMW, BN = 64 * WNW;
  constexpr int WAVES = WMW * WNW;
  constexpr int RG_A = BM / 16, RG_B = BN / 16;
  constexpr int NG = 2 * RG_A + 2 * RG_B;
  constexpr int GPW = NG / WAVES;
  static_assert(NG % WAVES == 0, "");

  __shared__ u16 sAB[2][NG * 512];

  int bx, by, bz;
  xcd_swizzle(bx, by, bz);

  const int tid  = threadIdx.x;
  const int wave = tid >> 6;
  const int lane = tid & 63;
  const int wm   = wave % WMW;
  const int wn   = wave / WMW;
  const int bm   = bx * BM;
  const int bn   = by * BN;
  const int koff = bz * Klen;
  const int lrow = lane & 15;
  const int lkc  = lane >> 4;
  const int sr   = lane >> 2;
  const int sk8  = (lane & 3) * 8;

  const u16* gptr[GPW];
#pragma unroll
  for (int t = 0; t < GPW; ++t) {
    int g = wave * GPW + t;
    const u16* base;
    int rowbase;
    if (g < 2 * RG_A) {
      int hl = g / RG_A, i = g % RG_A;
      base = hl ? Al : Ah;  rowbase = bm + i * 16;
    } else {
      int g2 = g - 2 * RG_A;
      int hl = g2 / RG_B, i = g2 % RG_B;
      base = hl ? Bl : Bh;  rowbase = bn + i * 16;
    }
    gptr[t] = base + (size_t)(rowbase + sr) * Kstride + koff + sk8;
  }

  f32x4 acc[4][4];
#pragma unroll
  for (int i = 0; i < 4; ++i)
#pragma unroll
    for (int j = 0; j < 4; ++j) acc[i][j] = (f32x4){0.f, 0.f, 0.f, 0.f};

#define STAGE(b, kk)                                             \
  {                                                              \
    _Pragma("unroll")                                            \
    for (int t = 0; t < GPW; ++t)                                \
      gload16(gptr[t] + (kk), &sAB[b][(wave * GPW + t) * 512]);  \
  }

  STAGE(0, 0);
  asm volatile("s_waitcnt vmcnt(0)" ::: "memory");
  __syncthreads();

  int buf = 0;
  for (int k0 = 0; k0 < Klen; k0 += 32) {
    if (k0 + 32 < Klen) STAGE(buf ^ 1, k0 + 32);

    const u16* sb = sAB[buf];
    bf16x8 a_h[4], a_l[4], b_h[4], b_l[4];
#pragma unroll
    for (int i = 0; i < 4; ++i) {
      a_h[i] = *(const bf16x8*)&sb[(0 * RG_A + wm * 4 + i) * 512 + lrow * 32 + lkc * 8];
      a_l[i] = *(const bf16x8*)&sb[(1 * RG_A + wm * 4 + i) * 512 + lrow * 32 + lkc * 8];
      b_h[i] = *(const bf16x8*)&sb[(2 * RG_A + 0 * RG_B + wn * 4 + i) * 512 + lrow * 32 + lkc * 8];
      b_l[i] = *(const bf16x8*)&sb[(2 * RG_A + 1 * RG_B + wn * 4 + i) * 512 + lrow * 32 + lkc * 8];
    }
#pragma unroll
    for (int i = 0; i < 4; ++i)
#pragma unroll
      for (int j = 0; j < 4; ++j) {
        acc[i][j] = __builtin_amdgcn_mfma_f32_16x16x32_bf16(a_h[i], b_h[j], acc[i][j], 0, 0, 0);
        acc[i][j] = __builtin_amdgcn_mfma_f32_16x16x32_bf16(a_l[i], b_h[j], acc[i][j], 0, 0, 0);
        acc[i][j] = __builtin_amdgcn_mfma_f32_16x16x32_bf16(a_h[i], b_l[j], acc[i][j], 0, 0, 0);
      }

    asm volatile("s_waitcnt vmcnt(0)" ::: "memory");
    __syncthreads();
    buf ^= 1;
  }
#undef STAGE

  const int r0 = (lane >> 4) * 4;
  if (!GATE) {
    float* Cs = C + (size_t)bz * c_slice;
#pragma unroll
    for (int j = 0; j < 4; ++j) {
      int col = bn + wn * 64 + j * 16 + lrow;
      if (col >= N) continue;
      float bv = bias ? bias[col] : 0.f;
#pragma unroll
      for (int i = 0; i < 4; ++i) {
        int rowb = bm + wm * 64 + i * 16 + r0;
#pragma unroll
        for (int r = 0; r < 4; ++r)
          Cs[(size_t)(rowb + r) * ldc + col] = acc[i][j][r] + bv;
      }
    }
  } else {
#pragma unroll
    for (int j = 0; j < 4; ++j) {
      int col = bn + wn * 64 + j * 16 + lrow;     // p in [0,64)
#pragma unroll
      for (int i = 0; i < 4; ++i) {
        int rowb = bm + wm * 64 + i * 16 + r0;
#pragma unroll
        for (int r = 0; r < 4; ++r) {
          int row = rowb + r;                     // l*16 + h
          int l = row >> 4, h = row & 15;
          size_t ei = (size_t)l * 1024 + (h << 6) + col;
          float xsv = bf2f(xs_hi[ei]) + bf2f(xs_lo[ei]);
          float z = projz[(size_t)l * DPROJ + (h << 6) + col];
          float v = (acc[i][j][r] + Dv[h] * xsv) * (z / (1.f + expf(-z)));
          u16 hh = f2bf(v);
          yg_hi[ei] = hh;
          yg_lo[ei] = f2bf(v - bf2f(hh));
        }
      }
    }
  }
}

// ---------------------------------------------------------------------------
// out = sum of 4 split-K partials (float4-vectorized).
// ---------------------------------------------------------------------------
__global__ __launch_bounds__(256)
void reduce4_kernel(const float* __restrict__ p, float* __restrict__ o)
{
  const int n = L_SEQ * 512 / 4;
  int i = blockIdx.x * 256 + threadIdx.x;
  if (i >= n) return;
  float4 a = ((const float4*)p)[i];
  float4 b = ((const float4*)p)[i + n];
  float4 c = ((const float4*)p)[i + 2 * n];
  float4 d = ((const float4*)p)[i + 3 * n];
  float4 r;
  r.x = (a.x + b.x) + (c.x + d.x);
  r.y = (a.y + b.y) + (c.y + d.y);
  r.z = (a.z + b.z) + (c.z + d.z);
  r.w = (a.w + b.w) + (c.w + d.w);
  ((float4*)o)[i] = r;
}

// ---------------------------------------------------------------------------
// dt / lam in EXACT f32 from u . W_in rows. 16 lanes cooperate per (l,g)
// pair (parallel dot + shfl reduce) -> grid 512, not latency-bound.
// ---------------------------------------------------------------------------
__global__ __launch_bounds__(256)
void dtlam_kernel(const float* __restrict__ u, const float* __restrict__ W_in,
                  const float* __restrict__ b_in, const float* __restrict__ A_log,
                  float* __restrict__ dtg, float* __restrict__ alphag,
                  float* __restrict__ c0g, float* __restrict__ c1g)
{
  int tid  = blockIdx.x * 256 + threadIdx.x;   // 131072 threads
  int pair = tid >> 4;                          // 8192 = L*G
  int ln   = tid & 15;
  int l = pair >> 2, g = pair & 3;
  const float4* ur = (const float4*)(u + (size_t)l * 512) + ln * 8;
  const float4* wd = (const float4*)(W_in + (size_t)(OFF_DT + g) * 512) + ln * 8;
  const float4* wl = (const float4*)(W_in + (size_t)(OFF_DT + 4 + g) * 512) + ln * 8;
  float sd = 0.f, sl = 0.f;
#pragma unroll
  for (int k = 0; k < 8; ++k) {
    float4 a = ur[k], b = wd[k], c = wl[k];
    sd += a.x * b.x + a.y * b.y + a.z * b.z + a.w * b.w;
    sl += a.x * c.x + a.y * c.y + a.z * c.z + a.w * c.w;
  }
#pragma unroll
  for (int m = 1; m < 16; m <<= 1) {
    sd += __shfl_xor(sd, m, 64);
    sl += __shfl_xor(sl, m, 64);
  }
  if (ln == 0) {
    sd += b_in[OFF_DT + g];
    sl += b_in[OFF_DT + 4 + g];
    float dt  = (sd > 20.f) ? sd : log1pf(expf(sd));
    float lam = 1.f / (1.f + expf(-sl));
    float Ag  = -expf(A_log[g]);
    float al  = expf(dt * Ag);
    dtg[pair]    = dt;
    alphag[pair] = al;
    c0g[pair]    = 1.f - lam;
    c1g[pair]    = lam * al;
  }
}

// ---------------------------------------------------------------------------
// f64 inclusive cumsum of dt over L per group + f64-exact RoPE angle range
// reduction: angred[l,g,f] = (theta_f * cumdt) mod 2pi. grid=4, block=256.
// ---------------------------------------------------------------------------
__global__ __launch_bounds__(256)
void cumsum_dt_kernel(const float* __restrict__ dtg,
                      const float* __restrict__ theta_log,
                      float* __restrict__ cumdt, float* __restrict__ angred)
{
  const int g = blockIdx.x;
  const int t = threadIdx.x;
  constexpr int PER = L_SEQ / 256;  // 8
  __shared__ double ps[256];
  double th[16];
#pragma unroll
  for (int f = 0; f < 16; ++f) th[f] = exp((double)theta_log[g * 16 + f]);
  float loc[PER];
  double s = 0.0;
  int l0 = t * PER;
  for (int i = 0; i < PER; ++i) {
    loc[i] = dtg[(l0 + i) * 4 + g];
    s += (double)loc[i];
  }
  ps[t] = s;
  __syncthreads();
  for (int off = 1; off < 256; off <<= 1) {
    double v = (t >= off) ? ps[t - off] : 0.0;
    __syncthreads();
    ps[t] += v;
    __syncthreads();
  }
  double c = ps[t] - s;  // exclusive prefix
  const double inv2pi = 0.15915494309189535;
  const double twopi  = 6.283185307179586;
  for (int i = 0; i < PER; ++i) {
    c += (double)loc[i];
    cumdt[(l0 + i) * 4 + g] = (float)c;
#pragma unroll
    for (int f = 0; f < 16; ++f) {
      double rev = th[f] * c * inv2pi;
      double fr  = rev - floor(rev);
      angred[(size_t)(l0 + i) * 64 + g * 16 + f] = (float)(fr * twopi);
    }
  }
}

// ---------------------------------------------------------------------------
// Per-token: silu(xp) -> xs hi/lo split ; rms+bias+rope for B/C.
// Uses precomputed range-reduced angles (fast sincosf path).
// ---------------------------------------------------------------------------
__global__ __launch_bounds__(256)
void pertoken_kernel(const float* __restrict__ proj,
                     const float* __restrict__ angred,
                     const float* __restrict__ norm_B_w,
                     const float* __restrict__ norm_C_w,
                     const float* __restrict__ bias_B,
                     const float* __restrict__ bias_C,
                     u16* __restrict__ xs_hi, u16* __restrict__ xs_lo,
                     float* __restrict__ Brot,
                     float* __restrict__ Crot)
{
  const int l = blockIdx.x;
  const int t = threadIdx.x;
  const size_t prow = (size_t)l * DPROJ;

  for (int i = t; i < 1024; i += 256) {
    float x = proj[prow + OFF_X + i];
    float s = x / (1.f + expf(-x));
    u16 hh = f2bf(s);
    xs_hi[(size_t)l * 1024 + i] = hh;
    xs_lo[(size_t)l * 1024 + i] = f2bf(s - bf2f(hh));
  }

  const int g = t >> 6;
  const int e = t & 63;
  float bv = proj[prow + OFF_B + t];
  float cv = proj[prow + OFF_C + t];
  float ssb = bv * bv, ssc = cv * cv;
#pragma unroll
  for (int m = 1; m <= 32; m <<= 1) {
    ssb += __shfl_xor(ssb, m, 64);
    ssc += __shfl_xor(ssc, m, 64);
  }
  float nb = bv * rsqrtf(ssb * (1.f / 64.f) + 1e-5f) * norm_B_w[e] + bias_B[t];
  float nc = cv * rsqrtf(ssc * (1.f / 64.f) + 1e-5f) * norm_C_w[e] + bias_C[t];

  float ang = angred[(size_t)l * 64 + g * 16 + (e >> 2)];
  float ca, sa;
  sincosf(ang, &sa, &ca);   // arg in [0,2pi) -> cheap reduction path
  float nb2 = __shfl_xor(nb, 2, 64);
  float nc2 = __shfl_xor(nc, 2, 64);
  bool isre = ((e >> 1) & 1) == 0;
  float Bo, Co;
  if (isre) {
    Bo = nb * ca + nb2 * sa;   // theta = -ang
    Co = nc * ca - nc2 * sa;   // theta = +ang
  } else {
    Bo = nb * ca - nb2 * sa;
    Co = nc * ca + nc2 * sa;
  }
  Brot[(size_t)l * 256 + t] = Bo;
  Crot[(size_t)l * 256 + t] = Co;
}

// ---------------------------------------------------------------------------
// Scan: lane = p, per-thread state H[n=0..31] + uprev[n].
// grid = (NCH, G), block = 256 (4 waves = 4 heads of group g).
// WITH_Y=true writes y directly as bf16 hi/lo split.
// ---------------------------------------------------------------------------
template<bool WITH_Y>
__global__ __launch_bounds__(256)
void scan_chunk(const float* __restrict__ Brot, const float* __restrict__ Crot,
                const float* __restrict__ xup,
                const float* __restrict__ dtg, const float* __restrict__ alphag,
                const float* __restrict__ c0g, const float* __restrict__ c1g,
                const float* __restrict__ hstates_in,
                float* __restrict__ hlast_out,
                u16* __restrict__ yhi, u16* __restrict__ ylo)
{
  const int c   = blockIdx.x;
  const int g   = blockIdx.y;
  const int wid = threadIdx.x >> 6;
  const int p   = threadIdx.x & 63;
  const int h   = g * 4 + wid;
  const int l0  = c * SCHUNK;

  __shared__ float Bs[SCHUNK][64];
  __shared__ float Cs[SCHUNK][64];
  __shared__ float als[SCHUNK], c0s[SCHUNK], c1s[SCHUNK];

  for (int i = threadIdx.x; i < SCHUNK * 64; i += 256) {
    int l = i >> 6, e = i & 63;
    float dt = dtg[(l0 + l) * 4 + g];
    Bs[l][e] = dt * Brot[(size_t)(l0 + l) * 256 + g * 64 + e];
    if (WITH_Y) Cs[l][e] = Crot[(size_t)(l0 + l) * 256 + g * 64 + e];
  }
  if (threadIdx.x < SCHUNK) {
    int l = threadIdx.x;
    als[l] = alphag[(l0 + l) * 4 + g];
    c0s[l] = c0g[(l0 + l) * 4 + g];
    c1s[l] = c1g[(l0 + l) * 4 + g];
  }
  __syncthreads();

  float H[32], up[32];
  if (WITH_Y) {
    const float* hs = &hstates_in[(((size_t)c * 16 + h) * 64 + p) * 32];
#pragma unroll
    for (int q = 0; q < 8; ++q) {
      float4 v = *reinterpret_cast<const float4*>(hs + 4 * q);
      H[4 * q] = v.x; H[4 * q + 1] = v.y; H[4 * q + 2] = v.z; H[4 * q + 3] = v.w;
    }
  } else {
#pragma unroll
    for (int n = 0; n < 32; ++n) H[n] = 0.f;
  }

  if (c > 0) {
    const int lm = l0 - 1;
    const float dtm = dtg[lm * 4 + g];
    float2 X = *reinterpret_cast<const float2*>(&xup[((size_t)lm * 16 + h) * 128 + 2 * p]);
    float x0 = dtm * X.x, x1 = dtm * X.y;
#pragma unroll
    for (int n = 0; n < 32; ++n) {
      float2 Bv = *reinterpret_cast<const float2*>(&Brot[(size_t)lm * 256 + g * 64 + 2 * n]);
      up[n] = Bv.x * x0 + Bv.y * x1;
    }
  } else {
#pragma unroll
    for (int n = 0; n < 32; ++n) up[n] = 0.f;
  }

  for (int l = 0; l < SCHUNK; ++l) {
    float2 X = *reinterpret_cast<const float2*>(
        &xup[((size_t)(l0 + l) * 16 + h) * 128 + 2 * p]);
    const float al = als[l], cc0 = c0s[l], cc1 = c1s[l];
    float y0 = 0.f, y1 = 0.f;
#pragma unroll
    for (int n2 = 0; n2 < 16; ++n2) {
      float4 Bv = *reinterpret_cast<const float4*>(&Bs[l][4 * n2]);
      float uin0 = Bv.x * X.x + Bv.y * X.y;
      float uin1 = Bv.z * X.x + Bv.w * X.y;
      float ue0 = cc0 * uin0 + cc1 * up[2 * n2];
      float ue1 = cc0 * uin1 + cc1 * up[2 * n2 + 1];
      H[2 * n2]     = al * H[2 * n2]     + ue0;
      H[2 * n2 + 1] = al * H[2 * n2 + 1] + ue1;
      up[2 * n2] = uin0; up[2 * n2 + 1] = uin1;
      if (WITH_Y) {
        float4 Cv = *reinterpret_cast<const float4*>(&Cs[l][4 * n2]);
        y0 = fmaf(H[2 * n2], Cv.x, fmaf(H[2 * n2 + 1], Cv.z, y0));
        y1 = fmaf(H[2 * n2], Cv.y, fmaf(H[2 * n2 + 1], Cv.w, y1));
      }
    }
    if (WITH_Y) {
      size_t ofs = ((size_t)(l0 + l) * 16 + h) * 128 + 2 * p;
      u16 h0 = f2bf(y0), h1 = f2bf(y1);
      *(ushort2*)&yhi[ofs] = make_ushort2(h0, h1);
      *(ushort2*)&ylo[ofs] = make_ushort2(f2bf(y0 - bf2f(h0)), f2bf(y1 - bf2f(h1)));
    }
  }

  if (!WITH_Y) {
    float* hl = &hlast_out[(((size_t)c * 16 + h) * 64 + p) * 32];
#pragma unroll
    for (int q = 0; q < 8; ++q)
      *reinterpret_cast<float4*>(hl + 4 * q) =
          make_float4(H[4 * q], H[4 * q + 1], H[4 * q + 2], H[4 * q + 3]);
  }
}

// ---------------------------------------------------------------------------
// Scan pass B: cross-chunk combine, ILP-batched 8-wide.
// ---------------------------------------------------------------------------
__global__ __launch_bounds__(256)
void scan_passB(const float* __restrict__ hlast, const float* __restrict__ cumdt,
                const float* __restrict__ A_log, float* __restrict__ hstates)
{
  int idx = blockIdx.x * 256 + threadIdx.x;   // H * P * N = 32768
  int h = idx >> 11;
  int rem = idx & 2047;
  int g = h >> 2;
  float Ag = -expf(A_log[g]);
  float s = 0.f;
  for (int c0 = 0; c0 < NCH; c0 += 8) {
    float hlv[8], dec[8];
#pragma unroll
    for (int j = 0; j < 8; ++j) {
      int c = c0 + j;
      hlv[j] = hlast[((size_t)c * 16 + h) * 2048 + rem];
      float sd = cumdt[(c * SCHUNK + SCHUNK - 1) * 4 + g]
               - (c > 0 ? cumdt[(c * SCHUNK - 1) * 4 + g] : 0.f);
      dec[j] = expf(Ag * sd);
    }
#pragma unroll
    for (int j = 0; j < 8; ++j) {
      hstates[((size_t)(c0 + j) * 16 + h) * 2048 + rem] = s;
      s = fmaf(s, dec[j], hlv[j]);
    }
  }
}

}  // namespace

extern "C" void kernel_launch(void* const* d_in, const int* in_sizes, int n_in,
                              void* d_out, int out_size, void* d_ws, size_t ws_size,
                              hipStream_t stream)
{
  const float* u         = (const float*)d_in[0];
  const float* W_in      = (const float*)d_in[1];
  const float* b_in      = (const float*)d_in[2];
  const float* W_xup     = (const float*)d_in[3];
  const float* W_ydown   = (const float*)d_in[4];
  const float* A_log     = (const float*)d_in[5];
  const float* theta_log = (const float*)d_in[6];
  const float* Dvec      = (const float*)d_in[7];
  const float* norm_B_w  = (const float*)d_in[8];
  const float* norm_C_w  = (const float*)d_in[9];
  const float* bias_B    = (const float*)d_in[10];
  const float* bias_C    = (const float*)d_in[11];
  const float* W_out     = (const float*)d_in[12];
  float* out = (float*)d_out;

  // ---- f32 workspace carve (floats) ----
  float* proj    = (float*)d_ws;                    // 2048*2568
  float* xsreg   = proj    + (size_t)L_SEQ * DPROJ; // 2048*1024 floats (xs hi+lo u16)
  float* dtg     = xsreg   + (size_t)L_SEQ * 1024;  // 2048*4 each
  float* alphag  = dtg     + L_SEQ * 4;
  float* c0g     = alphag  + L_SEQ * 4;
  float* c1g     = c0g     + L_SEQ * 4;
  float* cumdt   = c1g     + L_SEQ * 4;
  float* angred  = cumdt   + L_SEQ * 4;             // 2048*64
  float* Brot    = angred  + (size_t)L_SEQ * 64;    // 2048*256
  float* Crot    = Brot    + (size_t)L_SEQ * 256;
  float* xup     = Crot    + (size_t)L_SEQ * 256;   // 32768*128
  float* y128s   = xup     + (size_t)32768 * 128;   // slot: 32768*128 floats
  float* rAf     = y128s   + (size_t)32768 * 128;   // u16 region (see below)
  float* hlast   = rAf     + (size_t)5100000;       // NCH*16*2048 = 4.19M floats
  float* hstates = hlast   + (size_t)NCH * 16 * 2048;
  float* partials = y128s;                          // alias (y128 bf16 dead by out gemm)

  // xs hi/lo live in the xsreg slot (u16 planes)
  u16* xs_hi = (u16*)xsreg;
  u16* xs_lo = xs_hi + (size_t)L_SEQ * 1024;
  // y128 hi/lo live in the y128s slot
  u16* y128_hi = (u16*)y128s;
  u16* y128_lo = y128_hi + (size_t)32768 * 128;

  // ---- bf16 hi/lo region A (u16): persistent weights + u + yg ----
  u16* rA = (u16*)rAf;
  u16* win_hi  = rA;                                  // 2688*512
  u16* win_lo  = win_hi  + (size_t)2688 * 512;
  u16* wxup_hi = win_lo  + (size_t)2688 * 512;        // 128*64
  u16* wxup_lo = wxup_hi + (size_t)128 * 64;
  u16* wyd_hi  = wxup_lo + (size_t)128 * 64;          // 64*128
  u16* wyd_lo  = wyd_hi  + (size_t)64 * 128;
  u16* wout_hi = wyd_lo  + (size_t)64 * 128;          // 512*1024
  u16* wout_lo = wout_hi + (size_t)512 * 1024;
  u16* u_hi    = wout_lo + (size_t)512 * 1024;        // 2048*512
  u16* u_lo    = u_hi    + (size_t)2048 * 512;
  u16* yg_hi   = u_lo    + (size_t)2048 * 512;        // 2048*1024
  u16* yg_lo   = yg_hi   + (size_t)2048 * 1024;

  // 1. all converts (weights + u) in ONE launch; proj GEMM
  convert_all<<<dim3(2896), 256, 0, stream>>>(
      W_in, W_xup, W_ydown, W_out, u,
      win_hi, win_lo, wxup_hi, wxup_lo, wyd_hi, wyd_lo, wout_hi, wout_lo,
      u_hi, u_lo);
  gemm_mfma<2, 2, false><<<dim3(16, 21, 1), 256, 0, stream>>>(
      u_hi, u_lo, win_hi, win_lo, b_in, proj, DPROJ, DPROJ, 512, 512, 0,
      nullptr, nullptr, nullptr, nullptr, nullptr, nullptr);

  // 2. dt/lam exact-f32 (16-lane parallel dots); 3. f64 cumsum + angle table
  dtlam_kernel<<<dim3(512), 256, 0, stream>>>(u, W_in, b_in, A_log, dtg, alphag, c0g, c1g);
  cumsum_dt_kernel<<<dim3(4), 256, 0, stream>>>(dtg, theta_log, cumdt, angred);

  // 4. per-token: silu(xp) -> xs hi/lo, rms+bias+rope -> Brot/Crot
  pertoken_kernel<<<dim3(L_SEQ), 256, 0, stream>>>(
      proj, angred, norm_B_w, norm_C_w, bias_B, bias_C,
      xs_hi, xs_lo, Brot, Crot);

  // 5. x_up = xs @ W_xup^T (MFMA)
  gemm_mfma<2, 2, false><<<dim3(256, 1, 1), 256, 0, stream>>>(
      xs_hi, xs_lo, wxup_hi, wxup_lo, nullptr, xup, 128, 128, 64, 64, 0,
      nullptr, nullptr, nullptr, nullptr, nullptr, nullptr);

  // 6-8. chunked scan (state-in-registers); scanC emits y128 bf16 hi/lo
  scan_chunk<false><<<dim3(NCH, 4), 256, 0, stream>>>(
      Brot, Crot, xup, dtg, alphag, c0g, c1g, nullptr, hlast, nullptr, nullptr);
  scan_passB<<<dim3(128), 256, 0, stream>>>(hlast, cumdt, A_log, hstates);
  scan_chunk<true><<<dim3(NCH, 4), 256, 0, stream>>>(
      Brot, Crot, xup, dtg, alphag, c0g, c1g, hstates, nullptr, y128_hi, y128_lo);

  // 9+10. ydown GEMM with fused gate epilogue -> yg hi/lo directly
  gemm_mfma<2, 1, true><<<dim3(256, 1, 1), 128, 0, stream>>>(
      y128_hi, y128_lo, wyd_hi, wyd_lo, nullptr, nullptr, 0, 64, 128, 128, 0,
      Dvec, xs_hi, xs_lo, proj, yg_hi, yg_lo);

  // 11. out = yg @ W_out^T (MFMA, split-K=4 into partials) ; reduce
  gemm_mfma<2, 2, false><<<dim3(16, 4, 4), 256, 0, stream>>>(
      yg_hi, yg_lo, wout_hi, wout_lo, nullptr, partials, 512, 512, 1024, 256,
      (size_t)L_SEQ * 512,
      nullptr, nullptr, nullptr, nullptr, nullptr, nullptr);
  reduce4_kernel<<<dim3(1024), 256, 0, stream>>>(partials, out);
}